// Round 1
// baseline (595.487 us; speedup 1.0000x reference)
//
#include <hip/hip_runtime.h>

#define F 16

// --- degree count: deg[dst[e]] += 1 -----------------------------------------
__global__ void deg_kernel(const int* __restrict__ dst, float* __restrict__ deg, int E) {
    int e = blockIdx.x * blockDim.x + threadIdx.x;
    if (e < E) atomicAdd(&deg[dst[e]], 1.0f);
}

// --- dinv = rsqrt(deg + 1)  (self-loop adds 1; always > 0) ------------------
__global__ void dinv_kernel(float* __restrict__ deg, int n) {
    int i = blockIdx.x * blockDim.x + threadIdx.x;
    if (i < n) deg[i] = rsqrtf(deg[i] + 1.0f);
}

// --- fused linear (+optional pre-aggregation epilogue) ----------------------
// mode 0: feed = in[i,j]                      (layer-1: feed = x)
// mode 1: feed = relu(dinv[i]*(acc[i,j]+in[i,j]) + bias[j])   (layer-2 input)
// out[i,j] = (sum_k feed[i,k] * W[k,j]) * dinv[i]
// 256 threads = 16 nodes/block, 16 feats/node. In-place (out==in) is safe:
// each block reads its rows into LDS before writing them.
__global__ void linear_kernel(const float* __restrict__ in,
                              const float* __restrict__ acc,
                              const float* __restrict__ dinv,
                              const float* __restrict__ W,
                              const float* __restrict__ bias,
                              float* __restrict__ out,
                              int n, int mode) {
    __shared__ float Ws[F * F];
    __shared__ float As[16][F + 1];
    int t = threadIdx.x;
    Ws[t] = W[t];                       // 256 threads load 16x16 W
    int nb = t >> 4;                    // node within block
    int j  = t & 15;                    // output feature
    int i  = blockIdx.x * 16 + nb;
    float di = 0.f, v = 0.f;
    if (i < n) {
        di = dinv[i];
        v  = in[i * F + j];
        if (mode) {
            v = di * (acc[i * F + j] + v) + bias[j];
            v = fmaxf(v, 0.f);
        }
    }
    As[nb][j] = v;
    __syncthreads();
    if (i < n) {
        float s = 0.f;
#pragma unroll
        for (int k = 0; k < F; ++k) s += As[nb][k] * Ws[k * F + j];
        out[i * F + j] = s * di;
    }
}

// --- edge scatter: acc[dst,:] += h[src,:], 16 lanes per edge ----------------
__global__ void scatter_kernel(const int* __restrict__ src, const int* __restrict__ dst,
                               const float* __restrict__ h, float* __restrict__ acc, int E) {
    int t = blockIdx.x * blockDim.x + threadIdx.x;
    int e = t >> 4;
    int j = t & 15;
    if (e < E) {
        int s = src[e], d = dst[e];
        atomicAdd(&acc[d * F + j], h[s * F + j]);
    }
}

// --- final epilogue: out = dinv*(acc + h') + b ------------------------------
__global__ void out_kernel(const float* __restrict__ acc, const float* __restrict__ h,
                           const float* __restrict__ dinv, const float* __restrict__ bias,
                           float* __restrict__ out, int n) {
    int t = blockIdx.x * blockDim.x + threadIdx.x;
    if (t < n * F) {
        int i = t >> 4, j = t & 15;
        out[t] = dinv[i] * (acc[t] + h[t]) + bias[j];
    }
}

extern "C" void kernel_launch(void* const* d_in, const int* in_sizes, int n_in,
                              void* d_out, int out_size, void* d_ws, size_t ws_size,
                              hipStream_t stream) {
    const float* x  = (const float*)d_in[0];
    const int*   ei = (const int*)d_in[1];
    const float* W1 = (const float*)d_in[2];
    const float* b1 = (const float*)d_in[3];
    const float* W2 = (const float*)d_in[4];
    const float* b2 = (const float*)d_in[5];
    float* outp = (float*)d_out;

    const int N = in_sizes[0] / F;   // 100000
    const int E = in_sizes[1] / 2;   // 3200000
    const int* src = ei;
    const int* dst = ei + E;

    // workspace layout (floats): dinv[N] | h[16N] | acc[16N]
    float* dinv = (float*)d_ws;
    float* h    = dinv + N;
    float* acc  = h + (size_t)F * N;

    // zero deg (reuses dinv slot) and acc — harness poisons ws with 0xAA
    hipMemsetAsync(dinv, 0, (size_t)N * sizeof(float), stream);
    hipMemsetAsync(acc,  0, (size_t)F * N * sizeof(float), stream);

    deg_kernel<<<(E + 255) / 256, 256, 0, stream>>>(dst, dinv, E);
    dinv_kernel<<<(N + 255) / 256, 256, 0, stream>>>(dinv, N);

    // layer 1: h = (x @ W1) * dinv
    linear_kernel<<<(N + 15) / 16, 256, 0, stream>>>(x, nullptr, dinv, W1, nullptr, h, N, 0);
    scatter_kernel<<<((size_t)E * F + 255) / 256, 256, 0, stream>>>(src, dst, h, acc, E);

    // mid: a1 = relu(dinv*(acc+h)+b1); h = (a1 @ W2) * dinv   (in-place)
    linear_kernel<<<(N + 15) / 16, 256, 0, stream>>>(h, acc, dinv, W2, b1, h, N, 1);

    hipMemsetAsync(acc, 0, (size_t)F * N * sizeof(float), stream);
    scatter_kernel<<<((size_t)E * F + 255) / 256, 256, 0, stream>>>(src, dst, h, acc, E);

    out_kernel<<<((size_t)N * F + 255) / 256, 256, 0, stream>>>(acc, h, dinv, b2, outp, N);
}